// Round 1
// baseline (920.814 us; speedup 1.0000x reference)
//
#include <hip/hip_runtime.h>
#include <math.h>

#define BB 64
#define TT 4096
#define CC 128
#define NQ 64
#define TCH 256   // t-rows per apply block

// ---------------- Kernel 1: per-(b,c) row sort + quantile table ----------------
__global__ __launch_bounds__(256) void quantile_kernel(const float* __restrict__ x,
                                                       float* __restrict__ qtab) {
    __shared__ float s[TT];
    const int row = blockIdx.x;          // row = b*CC + c
    const int b = row >> 7;              // / CC
    const int c = row & (CC - 1);        // % CC
    const float* xrow = x + (size_t)b * TT * CC + c;
    const int tid = threadIdx.x;

    // strided load of the time series for this (b,c)
    for (int t = tid; t < TT; t += 256) s[t] = xrow[(size_t)t * CC];
    __syncthreads();

    // bitonic sort (ascending) of TT elements in LDS
    for (int k = 2; k <= TT; k <<= 1) {
        for (int j = k >> 1; j > 0; j >>= 1) {
            for (int i = tid; i < TT; i += 256) {
                int ixj = i ^ j;
                if (ixj > i) {
                    float a = s[i], bvl = s[ixj];
                    bool up = ((i & k) == 0);
                    if ((a > bvl) == up) { s[i] = bvl; s[ixj] = a; }
                }
            }
            __syncthreads();
        }
    }

    // quantiles: position = (q+0.5)*T/Q - 0.5 ; linear interp between floor/ceil
    if (tid < NQ) {
        float position = (tid + 0.5f) * ((float)TT / (float)NQ) - 0.5f;
        if (position < 0.0f) position = 0.0f;
        if (position > (float)(TT - 1)) position = (float)(TT - 1);
        int pi = (int)position;
        if (pi > TT - 2) pi = TT - 2;
        if (pi < 0) pi = 0;
        float frac = position - (float)pi;
        frac = fminf(fmaxf(frac, 0.0f), 1.0f);
        float qv = s[pi] * (1.0f - frac) + s[pi + 1] * frac;
        qtab[(size_t)row * NQ + tid] = qv;
    }
}

// ---------------- Kernel 2: CDF interp + probit ----------------
__global__ __launch_bounds__(256) void apply_kernel(const float* __restrict__ x,
                                                    const float* __restrict__ qtab,
                                                    float* __restrict__ out) {
    __shared__ float qt[CC][NQ + 1];     // +1 pad: break bank conflicts
    const int b = blockIdx.x;            // 0..BB-1
    const int tch = blockIdx.y;          // 0..TT/TCH-1
    const int tid = threadIdx.x;

    // stage the whole quantile table for this batch b (CC*NQ floats, coalesced)
    const float* qsrc = qtab + (size_t)b * CC * NQ;
    for (int i = tid; i < CC * NQ; i += 256) {
        qt[i >> 6][i & (NQ - 1)] = qsrc[i];
    }
    __syncthreads();

    const size_t base = (size_t)b * TT * CC + (size_t)tch * TCH * CC;
    const float* xp = x + base;
    float* op = out + base;
    const float invq = 1.0f / (float)NQ;

    for (int i = tid; i < TCH * CC; i += 256) {
        const int cc = i & (CC - 1);
        const float v = xp[i];

        // upper-bound count (searchsorted side='right'), capped at 63 (clip makes 64 == 63)
        int pos = 0;
        #pragma unroll
        for (int step = 32; step >= 1; step >>= 1) {
            int np = pos + step;
            pos = (qt[cc][np - 1] <= v) ? np : pos;
        }
        int idx = pos;
        if (idx < 1) idx = 1;
        if (idx > NQ - 1) idx = NQ - 1;

        const float x0 = qt[cc][idx - 1];
        const float x1 = qt[cc][idx];
        const float y0 = ((float)idx - 0.5f) * invq;
        const float slope = invq / fmaxf(x1 - x0, 1e-12f);
        float p = y0 + slope * (v - x0);
        p = fminf(fmaxf(p, 1e-6f), 1.0f - 1e-6f);
        op[i] = erfinvf(2.0f * p - 1.0f) * 1.4142135623730951f;
    }
}

extern "C" void kernel_launch(void* const* d_in, const int* in_sizes, int n_in,
                              void* d_out, int out_size, void* d_ws, size_t ws_size,
                              hipStream_t stream) {
    const float* x = (const float*)d_in[0];
    float* out = (float*)d_out;
    float* qtab = (float*)d_ws;          // BB*CC*NQ floats = 2 MB

    quantile_kernel<<<BB * CC, 256, 0, stream>>>(x, qtab);
    dim3 grid(BB, TT / TCH);
    apply_kernel<<<grid, 256, 0, stream>>>(x, qtab, out);
}

// Round 3
// 727.178 us; speedup vs baseline: 1.2663x; 1.2663x over previous
//
#include <hip/hip_runtime.h>
#include <math.h>

#define BB 64
#define TT 4096
#define CC 128
#define NQ 64
#define TCH 256   // t-rows per apply block

// ---- wave-wide digit match: mask of lanes whose 8-bit digit equals mine ----
__device__ __forceinline__ unsigned long long match8(unsigned d) {
    unsigned long long m = ~0ull;
    #pragma unroll
    for (int b = 0; b < 8; ++b) {
        unsigned long long bal = __ballot((d >> b) & 1u);
        m &= ((d >> b) & 1u) ? bal : ~bal;
    }
    return m;
}

// count of elements < v (LT) or <= v (!LT) in sorted base[0..N), N power of 2
template <int N, bool LT>
__device__ __forceinline__ unsigned count_sorted(const unsigned* base, unsigned v) {
    unsigned pos = 0;
    #pragma unroll
    for (unsigned step = N >> 1; step >= 1; step >>= 1) {
        unsigned probe = base[pos + step - 1];
        pos += (LT ? (probe < v) : (probe <= v)) ? step : 0;
    }
    unsigned probe = base[pos];              // pos <= N-1 here
    pos += (LT ? (probe < v) : (probe <= v)) ? 1u : 0u;
    return pos;                              // in [0, N]
}

// ---------------- Kernel 1: per-(b,c) row sort + quantile table ----------------
// Each wave STABLY radix-sorts its private 1024-element segment (wave-private
// histogram/cursor => per-pass stability is structural, no cross-wave races),
// then the 4 sorted runs are merged 4->2->1 by binary-search merge.
__global__ __launch_bounds__(256) void sort_quantile_kernel(const float* __restrict__ x,
                                                            float* __restrict__ qtab) {
    __shared__ unsigned A[TT];
    __shared__ unsigned Bb[TT];
    __shared__ unsigned hist[4][256];

    const int bid = blockIdx.x;
    // XCD swizzle: co-resident blocks on an XCD get consecutive c of same b
    const int row = ((bid & 7) << 10) | (bid >> 3);     // bijective, 8192 = 8*1024
    const int b = row >> 7, c = row & (CC - 1);
    const float* xrow = x + (size_t)b * TT * CC + c;
    const int tid = threadIdx.x;
    const int lane = tid & 63, wid = tid >> 6;
    const int seg = wid << 10;                          // wave-private [seg, seg+1024)

    // load own segment (strided gather) + order-preserving key transform
    for (int it = 0; it < 16; ++it) {
        int t = seg + it * 64 + lane;
        unsigned f = __float_as_uint(xrow[(size_t)t * CC]);
        A[t] = (f & 0x80000000u) ? ~f : (f | 0x80000000u);
    }

    unsigned* src = A;
    unsigned* dst = Bb;
    unsigned* cur = &hist[wid][0];

    for (int pass = 0; pass < 4; ++pass) {
        const int shift = pass << 3;

        // zero wave-private histogram
        for (int i = lane; i < 256; i += 64) cur[i] = 0;

        // histogram (leader of each digit-group adds group count)
        for (int it = 0; it < 16; ++it) {
            unsigned k = src[seg + it * 64 + lane];
            unsigned d = (k >> shift) & 255u;
            unsigned long long m = match8(d);
            int leader = __ffsll((long long)m) - 1;
            if (lane == leader) atomicAdd(&cur[d], (unsigned)__popcll(m));
        }

        // exclusive scan of 256 bins within the wave (lane owns 4 consecutive bins)
        unsigned s0 = cur[lane * 4 + 0], s1 = cur[lane * 4 + 1];
        unsigned s2 = cur[lane * 4 + 2], s3 = cur[lane * 4 + 3];
        unsigned S = s0 + s1 + s2 + s3;
        unsigned incl = S;
        #pragma unroll
        for (int off = 1; off < 64; off <<= 1) {
            unsigned n = __shfl_up(incl, off, 64);
            if (lane >= off) incl += n;
        }
        unsigned E = incl - S;                           // bins < lane*4
        cur[lane * 4 + 0] = E;
        cur[lane * 4 + 1] = E + s0;
        cur[lane * 4 + 2] = E + s0 + s1;
        cur[lane * 4 + 3] = E + s0 + s1 + s2;

        // STABLE scatter: iterations in index order, lanes ordered via `before`
        for (int it = 0; it < 16; ++it) {
            unsigned k = src[seg + it * 64 + lane];
            unsigned d = (k >> shift) & 255u;
            unsigned long long m = match8(d);
            int leader = __ffsll((long long)m) - 1;
            unsigned before = (unsigned)__popcll(m & ((1ull << lane) - 1ull));
            unsigned off = 0;
            if (lane == leader) off = atomicAdd(&cur[d], (unsigned)__popcll(m));
            off = (unsigned)__shfl((int)off, leader, 64);
            dst[seg + off + before] = k;
        }

        unsigned* tmp = src; src = dst; dst = tmp;
    }
    // 4 sorted 1024-runs in A (even number of ping-pongs)
    __syncthreads();

    // merge level 1: (run0,run1)->Bb[0:2048], (run2,run3)->Bb[2048:4096]
    for (int j = 0; j < 16; ++j) {
        int e = j * 256 + tid;                  // striped: conflict-free own-loads
        int base = e & 2048;                    // pair base
        int e2 = e & 2047;
        int run = e2 >> 10;
        int i = e2 & 1023;
        unsigned v = A[e];
        const unsigned* other = &A[base + ((1 - run) << 10)];
        unsigned cnt = (run == 0) ? count_sorted<1024, true>(other, v)
                                  : count_sorted<1024, false>(other, v);
        Bb[base + i + cnt] = v;
    }
    __syncthreads();

    // merge level 2: -> A[0:4096]
    for (int j = 0; j < 16; ++j) {
        int e = j * 256 + tid;
        int run = e >> 11;
        int i = e & 2047;
        unsigned v = Bb[e];
        const unsigned* other = &Bb[(1 - run) << 11];
        unsigned cnt = (run == 0) ? count_sorted<2048, true>(other, v)
                                  : count_sorted<2048, false>(other, v);
        A[i + cnt] = v;
    }
    __syncthreads();

    // quantiles: position = (q+0.5)*64 - 0.5 = 64q+31.5 exactly -> frac = 0.5
    if (tid < NQ) {
        int pi = (tid << 6) + 31;
        unsigned y0 = A[pi], y1 = A[pi + 1];
        float v0 = __uint_as_float((y0 & 0x80000000u) ? (y0 & 0x7fffffffu) : ~y0);
        float v1 = __uint_as_float((y1 & 0x80000000u) ? (y1 & 0x7fffffffu) : ~y1);
        qtab[(size_t)row * NQ + tid] = v0 * 0.5f + v1 * 0.5f;
    }
}

// ---------------- Kernel 2: CDF interp + probit ----------------
__global__ __launch_bounds__(256) void apply_kernel(const float* __restrict__ x,
                                                    const float* __restrict__ qtab,
                                                    float* __restrict__ out) {
    __shared__ float qt[CC][NQ + 1];     // +1 pad: break bank conflicts
    const int b = blockIdx.x;
    const int tch = blockIdx.y;
    const int tid = threadIdx.x;

    const float* qsrc = qtab + (size_t)b * CC * NQ;
    for (int i = tid; i < CC * NQ; i += 256) {
        qt[i >> 6][i & (NQ - 1)] = qsrc[i];
    }
    __syncthreads();

    const size_t base = (size_t)b * TT * CC + (size_t)tch * TCH * CC;
    const float* xp = x + base;
    float* op = out + base;
    const float invq = 1.0f / (float)NQ;

    for (int i = tid; i < TCH * CC; i += 256) {
        const int cc = i & (CC - 1);
        const float v = xp[i];

        // searchsorted(side='right') capped at 63 (clip makes 64 == 63)
        int pos = 0;
        #pragma unroll
        for (int step = 32; step >= 1; step >>= 1) {
            int np = pos + step;
            pos = (qt[cc][np - 1] <= v) ? np : pos;
        }
        int idx = pos;
        if (idx < 1) idx = 1;
        if (idx > NQ - 1) idx = NQ - 1;

        const float x0 = qt[cc][idx - 1];
        const float x1 = qt[cc][idx];
        const float y0 = ((float)idx - 0.5f) * invq;
        const float slope = invq / fmaxf(x1 - x0, 1e-12f);
        float p = y0 + slope * (v - x0);
        p = fminf(fmaxf(p, 1e-6f), 1.0f - 1e-6f);
        op[i] = erfinvf(2.0f * p - 1.0f) * 1.4142135623730951f;
    }
}

extern "C" void kernel_launch(void* const* d_in, const int* in_sizes, int n_in,
                              void* d_out, int out_size, void* d_ws, size_t ws_size,
                              hipStream_t stream) {
    const float* x = (const float*)d_in[0];
    float* out = (float*)d_out;
    float* qtab = (float*)d_ws;          // BB*CC*NQ floats = 2 MB

    sort_quantile_kernel<<<BB * CC, 256, 0, stream>>>(x, qtab);
    dim3 grid(BB, TT / TCH);
    apply_kernel<<<grid, 256, 0, stream>>>(x, qtab, out);
}

// Round 4
// 397.826 us; speedup vs baseline: 2.3146x; 1.8279x over previous
//
#include <hip/hip_runtime.h>
#include <math.h>

#define BB 64
#define TT 4096
#define CC 128
#define NQ 64
#define TCH 256   // t-rows per apply block

// bijective LDS word-index swizzle: XOR bits[4:2] with bits[6:4] (b128-friendly)
#define SWZ(i) ((i) ^ ((((i) >> 4) & 7) << 2))

// ---- wave-wide digit match: mask of lanes whose 8-bit digit equals mine ----
__device__ __forceinline__ unsigned long long match8(unsigned d) {
    unsigned long long m = ~0ull;
    #pragma unroll
    for (int b = 0; b < 8; ++b) {
        unsigned long long bal = __ballot((d >> b) & 1u);
        m &= ((d >> b) & 1u) ? bal : ~bal;
    }
    return m;
}

// popcount of (m & lanes-below-me)
__device__ __forceinline__ unsigned mbcnt64(unsigned long long m) {
    return __builtin_amdgcn_mbcnt_hi((unsigned)(m >> 32),
           __builtin_amdgcn_mbcnt_lo((unsigned)(m & 0xFFFFFFFFull), 0u));
}

// ---------------- Kernel 1: per-(b,c) row sort + quantile table ----------------
// Wave-private stable LSD radix (per-lane atomic histogram; ballot-ordered
// scatter), then merge-path level-1 merge (4 runs -> 2 runs of 2048) and
// direct merge-path SELECTION of the 128 needed ranks (no level-2 merge).
__global__ __launch_bounds__(256) void sort_quantile_kernel(const float* __restrict__ x,
                                                            float* __restrict__ qtab) {
    __shared__ unsigned A[TT];
    __shared__ unsigned Bb[TT];
    __shared__ unsigned hist[4][256];

    const int bid = blockIdx.x;
    // XCD swizzle: co-resident blocks on an XCD get consecutive c of same b
    const int row = ((bid & 7) << 10) | (bid >> 3);
    const int b = row >> 7, c = row & (CC - 1);
    const float* xrow = x + (size_t)b * TT * CC + c;
    const int tid = threadIdx.x;
    const int lane = tid & 63, wid = tid >> 6;
    const int seg = wid << 10;                   // wave-private [seg, seg+1024)

    // load own segment (strided gather) + order-preserving key transform
    #pragma unroll
    for (int it = 0; it < 16; ++it) {
        int t = seg + (it << 6) + lane;
        unsigned f = __float_as_uint(xrow[(size_t)t * CC]);
        A[t] = (f & 0x80000000u) ? ~f : (f | 0x80000000u);
    }

    unsigned* src = A;
    unsigned* dst = Bb;
    unsigned* cur = &hist[wid][0];
    unsigned kk[16];

    for (int pass = 0; pass < 4; ++pass) {
        const int shift = pass << 3;

        // zero wave-private histogram (one b128 per lane)
        ((uint4*)cur)[lane] = make_uint4(0u, 0u, 0u, 0u);

        // histogram: plain per-lane LDS atomics (no ordering needed here)
        #pragma unroll
        for (int it = 0; it < 16; ++it) {
            unsigned k = src[seg + (it << 6) + lane];
            kk[it] = k;
            atomicAdd(&cur[(k >> shift) & 255u], 1u);
        }

        // exclusive scan of 256 bins within the wave (lane owns 4 bins, b128 I/O)
        uint4 sv = ((uint4*)cur)[lane];
        unsigned S = sv.x + sv.y + sv.z + sv.w;
        unsigned incl = S;
        #pragma unroll
        for (int off = 1; off < 64; off <<= 1) {
            unsigned n = __shfl_up(incl, off, 64);
            if (lane >= off) incl += n;
        }
        unsigned E = incl - S;
        ((uint4*)cur)[lane] = make_uint4(E, E + sv.x, E + sv.x + sv.y,
                                         E + sv.x + sv.y + sv.z);

        // STABLE scatter: ballot-ordered within digit; read base then leader adds
        #pragma unroll
        for (int it = 0; it < 16; ++it) {
            unsigned k = kk[it];
            unsigned d = (k >> shift) & 255u;
            unsigned long long m = match8(d);
            unsigned before = mbcnt64(m);            // same-digit lanes below me
            unsigned base = cur[d];                  // pre-add value (program order)
            if (before == 0u) atomicAdd(&cur[d], (unsigned)__popcll(m));
            dst[seg + base + before] = k;
        }

        unsigned* tmp = src; src = dst; dst = tmp;
    }
    // 4 sorted 1024-runs in A (even number of ping-pongs)
    __syncthreads();

    // ---- level-1 merge via merge-path: (run0,run1)->Bb[0:2048], (run2,run3)->Bb[2048:4096]
    {
        const int pair = tid >> 7;
        const unsigned* P = &A[pair << 11];      // A-run P[0:1024], B-run P[1024:2048]
        const int k0 = (tid & 127) << 4;         // my 16-output chunk start

        // diagonal search: smallest a with B[k0-a-1] < A[a]
        int lo = k0 - 1024; if (lo < 0) lo = 0;
        int hi = k0 < 1024 ? k0 : 1024;
        while (lo < hi) {
            int a = (lo + hi) >> 1;
            if (P[1024 + (k0 - a - 1)] < P[a]) hi = a; else lo = a + 1;
        }
        int ia = lo;                              // in [0,1024]
        int ib = 1024 + (k0 - lo);                // in [1024,2048]
        unsigned va = (ia < 1024) ? P[ia] : 0xFFFFFFFFu;
        unsigned vb = (ib < 2048) ? P[ib] : 0xFFFFFFFFu;

        unsigned rr[16];
        #pragma unroll
        for (int j = 0; j < 16; ++j) {
            bool ta = (va <= vb);                 // tie -> A first
            rr[j] = ta ? va : vb;
            int nidx = (ta ? ia : ib) + 1;
            int lim  = ta ? 1024 : 2048;
            int ridx = nidx < 2047 ? nidx : 2047; // clamp: keep read in bounds
            unsigned nv = P[ridx];
            nv = (nidx < lim) ? nv : 0xFFFFFFFFu;
            if (ta) { ia = nidx; va = nv; } else { ib = nidx; vb = nv; }
        }

        const int obase = (pair << 11) + k0;
        #pragma unroll
        for (int jb = 0; jb < 4; ++jb) {
            int w = obase + (jb << 2);            // 4-aligned; SWZ keeps contiguity
            *(uint4*)&Bb[SWZ(w)] =
                make_uint4(rr[jb * 4 + 0], rr[jb * 4 + 1], rr[jb * 4 + 2], rr[jb * 4 + 3]);
        }
    }
    __syncthreads();

    // ---- rank selection: ranks 64q+31 (+1) from the two 2048-runs in Bb ----
    if (tid < 128) {
        const int q = tid >> 1;
        const int r = (q << 6) + 31 + (tid & 1);  // 0-indexed rank
        int lo = r - 2048; if (lo < 0) lo = 0;
        int hi = r < 2048 ? r : 2048;
        while (lo < hi) {
            int a = (lo + hi) >> 1;
            unsigned Av = Bb[SWZ(a)];
            unsigned Bv = Bb[SWZ(2048 + (r - a - 1))];
            if (Bv < Av) hi = a; else lo = a + 1;
        }
        int ai = lo, bi = r - lo;
        unsigned va = (ai < 2048) ? Bb[SWZ(ai)] : 0xFFFFFFFFu;
        unsigned vb = (bi < 2048) ? Bb[SWZ(2048 + bi)] : 0xFFFFFFFFu;
        unsigned e = (va <= vb) ? va : vb;
        float v = __uint_as_float((e & 0x80000000u) ? (e & 0x7fffffffu) : ~e);
        float vo = __shfl_xor(v, 1, 64);
        if ((tid & 1) == 0)
            qtab[(size_t)row * NQ + q] = (v + vo) * 0.5f;  // frac = 0.5 exactly
    }
}

// ---------------- Kernel 2: CDF interp + probit ----------------
__global__ __launch_bounds__(256) void apply_kernel(const float* __restrict__ x,
                                                    const float* __restrict__ qtab,
                                                    float* __restrict__ out) {
    __shared__ float qt[CC][NQ + 1];     // +1 pad: break bank conflicts
    const int b = blockIdx.x;
    const int tch = blockIdx.y;
    const int tid = threadIdx.x;

    const float* qsrc = qtab + (size_t)b * CC * NQ;
    for (int i = tid; i < CC * NQ; i += 256) {
        qt[i >> 6][i & (NQ - 1)] = qsrc[i];
    }
    __syncthreads();

    const size_t base = (size_t)b * TT * CC + (size_t)tch * TCH * CC;
    const float* xp = x + base;
    float* op = out + base;
    const float invq = 1.0f / (float)NQ;

    for (int i = tid; i < TCH * CC; i += 256) {
        const int cc = i & (CC - 1);
        const float v = xp[i];

        // searchsorted(side='right') capped at 63 (clip makes 64 == 63)
        int pos = 0;
        #pragma unroll
        for (int step = 32; step >= 1; step >>= 1) {
            int np = pos + step;
            pos = (qt[cc][np - 1] <= v) ? np : pos;
        }
        int idx = pos;
        if (idx < 1) idx = 1;
        if (idx > NQ - 1) idx = NQ - 1;

        const float x0 = qt[cc][idx - 1];
        const float x1 = qt[cc][idx];
        const float y0 = ((float)idx - 0.5f) * invq;
        const float slope = invq / fmaxf(x1 - x0, 1e-12f);
        float p = y0 + slope * (v - x0);
        p = fminf(fmaxf(p, 1e-6f), 1.0f - 1e-6f);
        op[i] = erfinvf(2.0f * p - 1.0f) * 1.4142135623730951f;
    }
}

extern "C" void kernel_launch(void* const* d_in, const int* in_sizes, int n_in,
                              void* d_out, int out_size, void* d_ws, size_t ws_size,
                              hipStream_t stream) {
    const float* x = (const float*)d_in[0];
    float* out = (float*)d_out;
    float* qtab = (float*)d_ws;          // BB*CC*NQ floats = 2 MB

    sort_quantile_kernel<<<BB * CC, 256, 0, stream>>>(x, qtab);
    dim3 grid(BB, TT / TCH);
    apply_kernel<<<grid, 256, 0, stream>>>(x, qtab, out);
}

// Round 5
// 291.367 us; speedup vs baseline: 3.1603x; 1.3654x over previous
//
#include <hip/hip_runtime.h>
#include <math.h>

#define BB 64
#define TT 4096
#define CC 128
#define NQ 64
#define TCH 256   // t-rows per apply block

// bijective LDS word-index swizzle: XOR bits[4:2] with bits[6:4].
// Preserves 16B (uint4) contiguity/alignment; spreads lane*16 bases over all banks.
#define SWZ(i) ((i) ^ ((((i) >> 4) & 7) << 2))

// compare-exchange on register array (unsigned keys, ascending)
#define CE(a,b) { unsigned lo_ = min(kk[a], kk[b]); unsigned hi_ = max(kk[a], kk[b]); \
                  kk[a] = lo_; kk[b] = hi_; }

// ---- one merge level: runs of R -> runs of 2R, thread handles 16 outputs ----
// src/dst are 4096-word LDS arrays, SWZ-indexed. Tie rule: A-run first.
template <int R>
__device__ __forceinline__ void merge_level(const unsigned* __restrict__ src,
                                            unsigned* __restrict__ dst, int tid) {
    const int o16 = tid << 4;                 // my output chunk [o16, o16+16)
    const int pb  = o16 & ~(2 * R - 1);       // pair base
    const int k0  = o16 - pb;                 // chunk start within pair
    const int A0  = pb, B0 = pb + R;

    // diagonal search: smallest a with B[k0-a-1] < A[a]
    int lo = k0 - R; if (lo < 0) lo = 0;
    int hi = k0 < R ? k0 : R;
    while (lo < hi) {
        int a = (lo + hi) >> 1;
        if (src[SWZ(B0 + (k0 - a - 1))] < src[SWZ(A0 + a)]) hi = a; else lo = a + 1;
    }
    int ja = lo, jb = k0 - lo;                // consumed counts in A-run / B-run

    unsigned va, vb;
    { int cl = ja < R - 1 ? ja : R - 1; unsigned nv = src[SWZ(A0 + cl)];
      va = (ja < R) ? nv : 0xFFFFFFFFu; }
    { int cl = jb < R - 1 ? jb : R - 1; unsigned nv = src[SWZ(B0 + cl)];
      vb = (jb < R) ? nv : 0xFFFFFFFFu; }

    unsigned rr[16];
    #pragma unroll
    for (int j = 0; j < 16; ++j) {
        bool ta = (va <= vb);                 // tie -> A first
        rr[j] = ta ? va : vb;
        int ni = (ta ? ja : jb) + 1;
        int cl = ni < R - 1 ? ni : R - 1;     // clamped in-bounds read
        unsigned nv = src[SWZ((ta ? A0 : B0) + cl)];
        nv = (ni < R) ? nv : 0xFFFFFFFFu;
        if (ta) { ja = ni; va = nv; } else { jb = ni; vb = nv; }
    }

    #pragma unroll
    for (int q = 0; q < 4; ++q)
        *(uint4*)&dst[SWZ(o16 + (q << 2))] =
            make_uint4(rr[q * 4 + 0], rr[q * 4 + 1], rr[q * 4 + 2], rr[q * 4 + 3]);
}

// ---------------- Kernel 1: per-(b,c) row sort + quantile table ----------------
// Register Batcher-16 sort per thread, then 7 merge-path levels (16->2048),
// then merge-path rank SELECTION of the 128 needed order statistics.
__global__ __launch_bounds__(256) void sort_quantile_kernel(const float* __restrict__ x,
                                                            float* __restrict__ qtab) {
    __shared__ unsigned A[TT];
    __shared__ unsigned Bb[TT];

    const int bid = blockIdx.x;
    // XCD swizzle: co-resident blocks on an XCD get consecutive c of same b
    const int row = ((bid & 7) << 10) | (bid >> 3);
    const int b = row >> 7, c = row & (CC - 1);
    const float* xrow = x + (size_t)b * TT * CC + c;
    const int tid = threadIdx.x;
    const int lane = tid & 63;
    const int seg = (tid >> 6) << 10;

    // load 16 elements (striped within wave segment: good L2 line locality),
    // transform to order-preserving u32 keys
    unsigned kk[16];
    #pragma unroll
    for (int j = 0; j < 16; ++j) {
        int e = seg + (j << 6) + lane;
        unsigned f = __float_as_uint(xrow[(size_t)e * CC]);
        kk[j] = (f & 0x80000000u) ? ~f : (f | 0x80000000u);
    }

    // Batcher odd-even merge sort network, n=16 (63 CEs, Knuth's construction)
    CE(0,1) CE(2,3) CE(4,5) CE(6,7) CE(8,9) CE(10,11) CE(12,13) CE(14,15)
    CE(0,2) CE(1,3) CE(4,6) CE(5,7) CE(8,10) CE(9,11) CE(12,14) CE(13,15)
    CE(1,2) CE(5,6) CE(9,10) CE(13,14)
    CE(0,4) CE(1,5) CE(2,6) CE(3,7) CE(8,12) CE(9,13) CE(10,14) CE(11,15)
    CE(2,4) CE(3,5) CE(10,12) CE(11,13)
    CE(1,2) CE(3,4) CE(5,6) CE(9,10) CE(11,12) CE(13,14)
    CE(0,8) CE(1,9) CE(2,10) CE(3,11) CE(4,12) CE(5,13) CE(6,14) CE(7,15)
    CE(4,8) CE(5,9) CE(6,10) CE(7,11)
    CE(2,4) CE(3,5) CE(6,8) CE(7,9) CE(10,12) CE(11,13)
    CE(1,2) CE(3,4) CE(5,6) CE(7,8) CE(9,10) CE(11,12) CE(13,14)

    // write my sorted 16-run to my output chunk (any disjoint partition is fine
    // for a comparison sort)
    {
        const int o16 = tid << 4;
        #pragma unroll
        for (int q = 0; q < 4; ++q)
            *(uint4*)&A[SWZ(o16 + (q << 2))] =
                make_uint4(kk[q * 4 + 0], kk[q * 4 + 1], kk[q * 4 + 2], kk[q * 4 + 3]);
    }
    __syncthreads();

    merge_level<16>(A, Bb, tid);  __syncthreads();
    merge_level<32>(Bb, A, tid);  __syncthreads();
    merge_level<64>(A, Bb, tid);  __syncthreads();
    merge_level<128>(Bb, A, tid); __syncthreads();
    merge_level<256>(A, Bb, tid); __syncthreads();
    merge_level<512>(Bb, A, tid); __syncthreads();
    merge_level<1024>(A, Bb, tid); __syncthreads();
    // Bb now holds two sorted 2048-runs (SWZ'd)

    // ---- rank selection: ranks 64q+31 (+1) from the two 2048-runs in Bb ----
    if (tid < 128) {
        const int q = tid >> 1;
        const int r = (q << 6) + 31 + (tid & 1);  // 0-indexed rank
        int lo = r - 2048; if (lo < 0) lo = 0;
        int hi = r < 2048 ? r : 2048;
        while (lo < hi) {
            int a = (lo + hi) >> 1;
            unsigned Av = Bb[SWZ(a)];
            unsigned Bv = Bb[SWZ(2048 + (r - a - 1))];
            if (Bv < Av) hi = a; else lo = a + 1;
        }
        int ai = lo, bi = r - lo;
        unsigned va = (ai < 2048) ? Bb[SWZ(ai)] : 0xFFFFFFFFu;
        unsigned vb = (bi < 2048) ? Bb[SWZ(2048 + bi)] : 0xFFFFFFFFu;
        unsigned e = (va <= vb) ? va : vb;
        float v = __uint_as_float((e & 0x80000000u) ? (e & 0x7fffffffu) : ~e);
        float vo = __shfl_xor(v, 1, 64);
        if ((tid & 1) == 0)
            qtab[(size_t)row * NQ + q] = (v + vo) * 0.5f;  // frac = 0.5 exactly
    }
}

// ---------------- Kernel 2: CDF interp + probit ----------------
__global__ __launch_bounds__(256) void apply_kernel(const float* __restrict__ x,
                                                    const float* __restrict__ qtab,
                                                    float* __restrict__ out) {
    __shared__ float qt[CC][NQ + 1];     // +1 pad: break bank conflicts
    const int b = blockIdx.x;
    const int tch = blockIdx.y;
    const int tid = threadIdx.x;

    const float* qsrc = qtab + (size_t)b * CC * NQ;
    for (int i = tid; i < CC * NQ; i += 256) {
        qt[i >> 6][i & (NQ - 1)] = qsrc[i];
    }
    __syncthreads();

    const size_t base = (size_t)b * TT * CC + (size_t)tch * TCH * CC;
    const float* xp = x + base;
    float* op = out + base;
    const float invq = 1.0f / (float)NQ;

    for (int i = tid; i < TCH * CC; i += 256) {
        const int cc = i & (CC - 1);
        const float v = xp[i];

        // searchsorted(side='right') capped at 63 (clip makes 64 == 63)
        int pos = 0;
        #pragma unroll
        for (int step = 32; step >= 1; step >>= 1) {
            int np = pos + step;
            pos = (qt[cc][np - 1] <= v) ? np : pos;
        }
        int idx = pos;
        if (idx < 1) idx = 1;
        if (idx > NQ - 1) idx = NQ - 1;

        const float x0 = qt[cc][idx - 1];
        const float x1 = qt[cc][idx];
        const float y0 = ((float)idx - 0.5f) * invq;
        const float slope = invq / fmaxf(x1 - x0, 1e-12f);
        float p = y0 + slope * (v - x0);
        p = fminf(fmaxf(p, 1e-6f), 1.0f - 1e-6f);
        op[i] = erfinvf(2.0f * p - 1.0f) * 1.4142135623730951f;
    }
}

extern "C" void kernel_launch(void* const* d_in, const int* in_sizes, int n_in,
                              void* d_out, int out_size, void* d_ws, size_t ws_size,
                              hipStream_t stream) {
    const float* x = (const float*)d_in[0];
    float* out = (float*)d_out;
    float* qtab = (float*)d_ws;          // BB*CC*NQ floats = 2 MB

    sort_quantile_kernel<<<BB * CC, 256, 0, stream>>>(x, qtab);
    dim3 grid(BB, TT / TCH);
    apply_kernel<<<grid, 256, 0, stream>>>(x, qtab, out);
}

// Round 6
// 248.040 us; speedup vs baseline: 3.7124x; 1.1747x over previous
//
#include <hip/hip_runtime.h>
#include <math.h>

#define BB 64
#define TT 4096
#define CC 128
#define NQ 64
#define TCH 256   // t-rows per apply block

// bijective LDS word-index swizzle: XOR bits[4:2] with bits[6:4].
// Preserves 16B (uint4) contiguity/alignment; spreads lane*16 bases over all banks.
#define SWZ(i) ((i) ^ ((((i) >> 4) & 7) << 2))

// compare-exchange on register array (unsigned keys, ascending)
#define CE(a,b) { unsigned lo_ = min(kk[a], kk[b]); unsigned hi_ = max(kk[a], kk[b]); \
                  kk[a] = lo_; kk[b] = hi_; }

// ---- cross-lane value get, three transports ----
// KIND 0: DPP (ARG = dpp_ctrl: 0xB1=^1, 0x4E=^2, 0x1B=^3, 0x141=^7, 0x140=^15)
// KIND 1: ds_swizzle xor ARG within 32-lane groups (ARG in {4,8,16,31})
// KIND 2: shfl_xor ARG across 64 lanes (ARG=63)
template <int KIND, int ARG>
__device__ __forceinline__ unsigned xget(unsigned v) {
    if constexpr (KIND == 0)
        return (unsigned)__builtin_amdgcn_update_dpp(0, (int)v, ARG, 0xF, 0xF, true);
    else if constexpr (KIND == 1)
        return (unsigned)__builtin_amdgcn_ds_swizzle((int)v, (ARG << 10) | 0x1F);
    else
        return (unsigned)__shfl_xor((int)v, ARG, 64);
}

// reversed first stage of a bitonic merge: (lane,i) <-> (lane^M, 15-i).
// low lanes keep min, high keep max. Pairs (i,15-i) handled together so both
// fetches read pre-update registers (lockstep hazard avoided).
template <int KIND, int ARG>
__device__ __forceinline__ void rev_stage(unsigned kk[16], bool low) {
    #pragma unroll
    for (int i = 0; i < 8; ++i) {
        unsigned a = kk[i], b = kk[15 - i];
        unsigned ta = xget<KIND, ARG>(b);   // partner's kk[15-i] pairs with my kk[i]
        unsigned tb = xget<KIND, ARG>(a);   // partner's kk[i] pairs with my kk[15-i]
        unsigned lo1 = min(a, ta), hi1 = max(a, ta);
        unsigned lo2 = min(b, tb), hi2 = max(b, tb);
        kk[i]      = low ? lo1 : hi1;
        kk[15 - i] = low ? lo2 : hi2;
    }
}

// straight cross-lane stage: same reg, lane^mask. low lanes keep min.
template <int KIND, int ARG>
__device__ __forceinline__ void str_stage(unsigned kk[16], bool low) {
    #pragma unroll
    for (int i = 0; i < 16; ++i) {
        unsigned t = xget<KIND, ARG>(kk[i]);
        unsigned lo = min(kk[i], t), hi = max(kk[i], t);
        kk[i] = low ? lo : hi;
    }
}

// in-lane bitonic cleanup of 16 regs (distances 8,4,2,1)
__device__ __forceinline__ void clean16(unsigned kk[16]) {
    #pragma unroll
    for (int d = 8; d >= 1; d >>= 1) {
        #pragma unroll
        for (int i = 0; i < 16; ++i) {
            if (!(i & d)) {
                int j = i | d;
                unsigned lo = min(kk[i], kk[j]);
                kk[j] = max(kk[i], kk[j]);
                kk[i] = lo;
            }
        }
    }
}

// ---- one LDS merge level: runs of R -> runs of 2R, thread handles 16 outputs ----
template <int R>
__device__ __forceinline__ void merge_level(const unsigned* __restrict__ src,
                                            unsigned* __restrict__ dst, int tid) {
    const int o16 = tid << 4;
    const int pb  = o16 & ~(2 * R - 1);
    const int k0  = o16 - pb;
    const int A0  = pb, B0 = pb + R;

    int lo = k0 - R; if (lo < 0) lo = 0;
    int hi = k0 < R ? k0 : R;
    while (lo < hi) {
        int a = (lo + hi) >> 1;
        if (src[SWZ(B0 + (k0 - a - 1))] < src[SWZ(A0 + a)]) hi = a; else lo = a + 1;
    }
    int ja = lo, jb = k0 - lo;

    unsigned va, vb;
    { int cl = ja < R - 1 ? ja : R - 1; unsigned nv = src[SWZ(A0 + cl)];
      va = (ja < R) ? nv : 0xFFFFFFFFu; }
    { int cl = jb < R - 1 ? jb : R - 1; unsigned nv = src[SWZ(B0 + cl)];
      vb = (jb < R) ? nv : 0xFFFFFFFFu; }

    unsigned rr[16];
    #pragma unroll
    for (int j = 0; j < 16; ++j) {
        bool ta = (va <= vb);
        rr[j] = ta ? va : vb;
        int ni = (ta ? ja : jb) + 1;
        int cl = ni < R - 1 ? ni : R - 1;
        unsigned nv = src[SWZ((ta ? A0 : B0) + cl)];
        nv = (ni < R) ? nv : 0xFFFFFFFFu;
        if (ta) { ja = ni; va = nv; } else { jb = ni; vb = nv; }
    }

    #pragma unroll
    for (int q = 0; q < 4; ++q)
        *(uint4*)&dst[SWZ(o16 + (q << 2))] =
            make_uint4(rr[q * 4 + 0], rr[q * 4 + 1], rr[q * 4 + 2], rr[q * 4 + 3]);
}

// ---------------- Kernel 1: per-(b,c) row sort + quantile table ----------------
// Per-wave fully in-register sort of 1024 elems (Batcher-16 + DPP/swizzle
// bitonic merges in blocked layout), one LDS merge-path level (->2048 runs),
// then merge-path rank SELECTION of the 128 needed order statistics.
__global__ __launch_bounds__(256) void sort_quantile_kernel(const float* __restrict__ x,
                                                            float* __restrict__ qtab) {
    __shared__ unsigned A[TT];
    __shared__ unsigned Bb[TT];

    const int bid = blockIdx.x;
    // XCD swizzle: co-resident blocks on an XCD get consecutive c of same b
    const int row = ((bid & 7) << 10) | (bid >> 3);
    const int b = row >> 7, c = row & (CC - 1);
    const float* xrow = x + (size_t)b * TT * CC + c;
    const int tid = threadIdx.x;
    const int lane = tid & 63;
    const int seg = (tid >> 6) << 10;            // wave's 1024-elem segment

    // load 16 elements, transform to order-preserving u32 keys
    unsigned kk[16];
    #pragma unroll
    for (int j = 0; j < 16; ++j) {
        int e = seg + (j << 6) + lane;
        unsigned f = __float_as_uint(xrow[(size_t)e * CC]);
        kk[j] = (f & 0x80000000u) ? ~f : (f | 0x80000000u);
    }

    // Batcher odd-even merge sort network, n=16 (63 CEs)
    CE(0,1) CE(2,3) CE(4,5) CE(6,7) CE(8,9) CE(10,11) CE(12,13) CE(14,15)
    CE(0,2) CE(1,3) CE(4,6) CE(5,7) CE(8,10) CE(9,11) CE(12,14) CE(13,15)
    CE(1,2) CE(5,6) CE(9,10) CE(13,14)
    CE(0,4) CE(1,5) CE(2,6) CE(3,7) CE(8,12) CE(9,13) CE(10,14) CE(11,15)
    CE(2,4) CE(3,5) CE(10,12) CE(11,13)
    CE(1,2) CE(3,4) CE(5,6) CE(9,10) CE(11,12) CE(13,14)
    CE(0,8) CE(1,9) CE(2,10) CE(3,11) CE(4,12) CE(5,13) CE(6,14) CE(7,15)
    CE(4,8) CE(5,9) CE(6,10) CE(7,11)
    CE(2,4) CE(3,5) CE(6,8) CE(7,9) CE(10,12) CE(11,13)
    CE(1,2) CE(3,4) CE(5,6) CE(7,8) CE(9,10) CE(11,12) CE(13,14)

    const bool l1  = (lane & 1)  == 0;
    const bool l2  = (lane & 2)  == 0;
    const bool l4  = (lane & 4)  == 0;
    const bool l8  = (lane & 8)  == 0;
    const bool l16 = (lane & 16) == 0;
    const bool l32 = (lane & 32) == 0;

    // ->32 (runs: 1 lane -> 2 lanes)
    rev_stage<0, 0xB1>(kk, l1); clean16(kk);
    // ->64
    rev_stage<0, 0x1B>(kk, l2);
    str_stage<0, 0xB1>(kk, l1); clean16(kk);
    // ->128
    rev_stage<0, 0x141>(kk, l4);
    str_stage<0, 0x4E>(kk, l2);
    str_stage<0, 0xB1>(kk, l1); clean16(kk);
    // ->256
    rev_stage<0, 0x140>(kk, l8);
    str_stage<1, 4>(kk, l4);
    str_stage<0, 0x4E>(kk, l2);
    str_stage<0, 0xB1>(kk, l1); clean16(kk);
    // ->512
    rev_stage<1, 31>(kk, l16);
    str_stage<1, 8>(kk, l8);
    str_stage<1, 4>(kk, l4);
    str_stage<0, 0x4E>(kk, l2);
    str_stage<0, 0xB1>(kk, l1); clean16(kk);
    // ->1024 (full wave)
    rev_stage<2, 63>(kk, l32);
    str_stage<1, 16>(kk, l16);
    str_stage<1, 8>(kk, l8);
    str_stage<1, 4>(kk, l4);
    str_stage<0, 0x4E>(kk, l2);
    str_stage<0, 0xB1>(kk, l1); clean16(kk);

    // wave's 1024-run is sorted, blocked: rank = lane*16 + i. Write to LDS.
    {
        const int o16 = tid << 4;
        #pragma unroll
        for (int q = 0; q < 4; ++q)
            *(uint4*)&A[SWZ(o16 + (q << 2))] =
                make_uint4(kk[q * 4 + 0], kk[q * 4 + 1], kk[q * 4 + 2], kk[q * 4 + 3]);
    }
    __syncthreads();

    merge_level<1024>(A, Bb, tid);
    __syncthreads();
    // Bb now holds two sorted 2048-runs (SWZ'd)

    // ---- rank selection: ranks 64q+31 (+1) from the two 2048-runs in Bb ----
    if (tid < 128) {
        const int q = tid >> 1;
        const int r = (q << 6) + 31 + (tid & 1);  // 0-indexed rank
        int lo = r - 2048; if (lo < 0) lo = 0;
        int hi = r < 2048 ? r : 2048;
        while (lo < hi) {
            int a = (lo + hi) >> 1;
            unsigned Av = Bb[SWZ(a)];
            unsigned Bv = Bb[SWZ(2048 + (r - a - 1))];
            if (Bv < Av) hi = a; else lo = a + 1;
        }
        int ai = lo, bi = r - lo;
        unsigned va = (ai < 2048) ? Bb[SWZ(ai)] : 0xFFFFFFFFu;
        unsigned vb = (bi < 2048) ? Bb[SWZ(2048 + bi)] : 0xFFFFFFFFu;
        unsigned e = (va <= vb) ? va : vb;
        float v = __uint_as_float((e & 0x80000000u) ? (e & 0x7fffffffu) : ~e);
        float vo = __shfl_xor(v, 1, 64);
        if ((tid & 1) == 0)
            qtab[(size_t)row * NQ + q] = (v + vo) * 0.5f;  // frac = 0.5 exactly
    }
}

// ---------------- Kernel 2: CDF interp + probit ----------------
__global__ __launch_bounds__(256) void apply_kernel(const float* __restrict__ x,
                                                    const float* __restrict__ qtab,
                                                    float* __restrict__ out) {
    __shared__ float qt[CC][NQ + 1];     // +1 pad: break bank conflicts
    const int b = blockIdx.x;
    const int tch = blockIdx.y;
    const int tid = threadIdx.x;

    const float* qsrc = qtab + (size_t)b * CC * NQ;
    for (int i = tid; i < CC * NQ; i += 256) {
        qt[i >> 6][i & (NQ - 1)] = qsrc[i];
    }
    __syncthreads();

    const size_t base = (size_t)b * TT * CC + (size_t)tch * TCH * CC;
    const float* xp = x + base;
    float* op = out + base;
    const float invq = 1.0f / (float)NQ;

    for (int i = tid; i < TCH * CC; i += 256) {
        const int cc = i & (CC - 1);
        const float v = xp[i];

        // searchsorted(side='right') capped at 63 (clip makes 64 == 63)
        int pos = 0;
        #pragma unroll
        for (int step = 32; step >= 1; step >>= 1) {
            int np = pos + step;
            pos = (qt[cc][np - 1] <= v) ? np : pos;
        }
        int idx = pos;
        if (idx < 1) idx = 1;
        if (idx > NQ - 1) idx = NQ - 1;

        const float x0 = qt[cc][idx - 1];
        const float x1 = qt[cc][idx];
        const float y0 = ((float)idx - 0.5f) * invq;
        const float slope = invq / fmaxf(x1 - x0, 1e-12f);
        float p = y0 + slope * (v - x0);
        p = fminf(fmaxf(p, 1e-6f), 1.0f - 1e-6f);
        op[i] = erfinvf(2.0f * p - 1.0f) * 1.4142135623730951f;
    }
}

extern "C" void kernel_launch(void* const* d_in, const int* in_sizes, int n_in,
                              void* d_out, int out_size, void* d_ws, size_t ws_size,
                              hipStream_t stream) {
    const float* x = (const float*)d_in[0];
    float* out = (float*)d_out;
    float* qtab = (float*)d_ws;          // BB*CC*NQ floats = 2 MB

    sort_quantile_kernel<<<BB * CC, 256, 0, stream>>>(x, qtab);
    dim3 grid(BB, TT / TCH);
    apply_kernel<<<grid, 256, 0, stream>>>(x, qtab, out);
}